// Round 7
// baseline (213.973 us; speedup 1.0000x reference)
//
#include <hip/hip_runtime.h>
#include <math.h>

#define NF 24
#define NU 64
#define NC 128
#define NB 8192
#define NP 276          // NF*(NF-1)/2
#define EPSV 1e-6f
#define QMIN  (-0.1f)
#define QSTEP (0.2f / 15.f)
#define QINV  (15.f / 0.2f)

// ---------------- KF: fused feature-LSE + structure weights + G2 fold. 24 blocks x 128 thr -------
__global__ void __launch_bounds__(NC)
kf_build(const float* __restrict__ feat,
         const float* __restrict__ class_logits,
         const float* __restrict__ structure_logits,
         const float* __restrict__ noise_uniform,
         float* __restrict__ g2,
         float* __restrict__ wbuf) {
    const int f = blockIdx.x;            // [0, NF)
    const int t = threadIdx.x;           // 128
    const int l = t & 31, g = t >> 5, c4 = l * 4;

    __shared__ float slice[NU][NC];      // 32 KB
    __shared__ float lse_sh[NC];
    __shared__ float cls[NC];
    __shared__ float weff_sh;

    #pragma unroll
    for (int i = 0; i < 16; ++i) {
        const int u = g * 16 + i;
        *(float4*)(&slice[u][c4]) =
            *(const float4*)(feat + ((size_t)f * NU + u) * NC + c4);
    }
    if (f == 0) cls[t] = class_logits[t];
    __syncthreads();

    float s = 0.f;
    #pragma unroll 8
    for (int u = 0; u < NU; ++u) s += __expf(slice[u][t]);
    lse_sh[t] = logf(s);

    if (t == 0) {
        if (f == 0) { weff_sh = 1.f; }
        else {
            const int i = f - 1;
            float z[NF]; float m = -INFINITY;
            #pragma unroll
            for (int j = 0; j < NF; ++j) {
                const float uu = noise_uniform[i * NF + j];
                const float gg = -logf(-logf(uu + EPSV) + EPSV);
                float zz = structure_logits[i * NF + j] + gg;
                if (j > f) zz = -1e30f;
                z[j] = zz; m = fmaxf(m, zz);
            }
            float ss = 0.f;
            #pragma unroll
            for (int j = 0; j < NF; ++j) { z[j] = __expf(z[j] - m); ss += z[j]; }
            weff_sh = z[f] / ss;
        }
    }
    if (f == 0 && t < NF - 1) {
        const int i = t;
        float z[NF]; float m = -INFINITY;
        #pragma unroll
        for (int j = 0; j < NF; ++j) {
            const float uu = noise_uniform[i * NF + j];
            const float gg = -logf(-logf(uu + EPSV) + EPSV);
            float zz = structure_logits[i * NF + j] + gg;
            if (j > i + 1) zz = -1e30f;
            z[j] = zz; m = fmaxf(m, zz);
        }
        float ss = 0.f;
        #pragma unroll
        for (int j = 0; j < NF; ++j) { z[j] = __expf(z[j] - m); ss += z[j]; }
        const float inv = 1.f / ss;
        #pragma unroll
        for (int j = 0; j < NF; ++j) wbuf[i * NF + j] = z[j] * inv;
    }
    __syncthreads();

    const float weff = weff_sh;
    float lcls = 0.f;
    if (f == 0) {
        float sc = 0.f;
        #pragma unroll
        for (int i = 0; i < NC; ++i) sc += __expf(cls[i]);
        lcls = logf(sc);
    }

    const float4 L = *(const float4*)(&lse_sh[c4]);
    #pragma unroll
    for (int i = 0; i < 16; ++i) {
        const int u = g * 16 + i;
        const float4 v = *(const float4*)(&slice[u][c4]);
        float4 r;
        r.x = weff * (v.x - L.x); r.y = weff * (v.y - L.y);
        r.z = weff * (v.z - L.z); r.w = weff * (v.w - L.w);
        if (f == 0) {
            const float4 cv = *(const float4*)(&cls[c4]);
            r.x += cv.x - lcls; r.y += cv.y - lcls;
            r.z += cv.z - lcls; r.w += cv.w - lcls;
        }
        *(float4*)(g2 + ((size_t)f * NU + u) * NC + c4) = r;
    }
}

// ---------------- K1q: stream aug, fixed-range int4 quant in flight + lse over u1 ----------------
// Block per (p,u2), 17664 blocks, no slice staging (2.5 KB LDS), high occupancy.
// Q layout [p][u2][u1][c] nibbles -> block writes contiguous 4 KB.
__global__ void __launch_bounds__(128)
k1_quant(const float* __restrict__ aug,
         unsigned short* __restrict__ Q4,
         float* __restrict__ lse_t) {
    const int pu2 = blockIdx.x;              // p*64 + u2
    const int p = pu2 >> 6, u2 = pu2 & 63;
    const int t = threadIdx.x;
    const int l = t & 31, g = t >> 5;        // group owns 16 u1's
    const int c4 = l * 4;

    __shared__ float sred[4][NC];

    const float* rb = aug + ((size_t)p * 4096 + u2) * NC + c4;   // [p][u1=0][u2][c4]
    unsigned short* qb = Q4 + (size_t)pu2 * 2048 + l;            // + u1*32

    float4 acc = {0.f, 0.f, 0.f, 0.f};
    #pragma unroll
    for (int i = 0; i < 16; ++i) {
        const int u1 = g * 16 + i;
        const float4 v = *(const float4*)(rb + (size_t)u1 * 8192);
        acc.x += __expf(v.x); acc.y += __expf(v.y);
        acc.z += __expf(v.z); acc.w += __expf(v.w);
        const unsigned int q0 = (unsigned int)fminf(fmaxf(rintf((v.x - QMIN) * QINV), 0.f), 15.f);
        const unsigned int q1 = (unsigned int)fminf(fmaxf(rintf((v.y - QMIN) * QINV), 0.f), 15.f);
        const unsigned int q2 = (unsigned int)fminf(fmaxf(rintf((v.z - QMIN) * QINV), 0.f), 15.f);
        const unsigned int q3 = (unsigned int)fminf(fmaxf(rintf((v.w - QMIN) * QINV), 0.f), 15.f);
        qb[u1 * 32] = (unsigned short)(q0 | (q1 << 4) | (q2 << 8) | (q3 << 12));
    }

    *(float4*)(&sred[g][c4]) = acc;
    __syncthreads();
    if (g == 0) {
        const float4 r0 = *(const float4*)(&sred[0][c4]);
        const float4 r1 = *(const float4*)(&sred[1][c4]);
        const float4 r2 = *(const float4*)(&sred[2][c4]);
        const float4 r3 = *(const float4*)(&sred[3][c4]);
        float4 L;
        L.x = logf(r0.x + r1.x + r2.x + r3.x);
        L.y = logf(r0.y + r1.y + r2.y + r3.y);
        L.z = logf(r0.z + r1.z + r2.z + r3.z);
        L.w = logf(r0.w + r1.w + r2.w + r3.w);
        *(float4*)(lse_t + (size_t)pu2 * NC + c4) = L;
    }
}

// ---------------- KG: fold gathered-lse sums into G2 (in place) ----------------
__global__ void __launch_bounds__(NC)
kg_fold(const float* __restrict__ lse_t,
        const float* __restrict__ wbuf,
        float* __restrict__ g2) {
    const int blk = blockIdx.x;          // [0, NF*NU)
    const int f = blk >> 6, u = blk & 63;
    const int c = threadIdx.x;
    float acc = 0.f;
    for (int fp = f + 1; fp < NF; ++fp) {
        const int p = fp * (fp - 1) / 2 + f;
        acc -= wbuf[(fp - 1) * NF + f] * lse_t[((size_t)p * NU + u) * NC + c];
    }
    g2[((size_t)f * NU + u) * NC + c] += acc;
}

// ---------------- K2: per-batch gather from int4 table (uint loads, 8 groups) ----------------
__global__ void __launch_bounds__(NC)
k2_gather(const int* __restrict__ x,
          const unsigned int* __restrict__ Qu,
          const float* __restrict__ g2,
          const float* __restrict__ wbuf,
          float* __restrict__ out) {
    const int b = blockIdx.x;
    const int t = threadIdx.x;                 // 128
    const int sub = t & 15;                    // uint index within 64 B row
    const int gg = t >> 4;                     // 8 groups of 16 lanes
    const int c8 = sub * 8;

    __shared__ int   xs[NF];
    __shared__ int   qoff[NP];
    __shared__ float ws_[NP];
    __shared__ float sred[8][NC];

    if (t < NF) xs[t] = x[b * NF + t];
    __syncthreads();

    for (int p = t; p < NP; p += NC) {
        int f = (int)((sqrtf(8.0f * (float)p + 1.0f) - 1.0f) * 0.5f) + 1;
        while (f * (f + 1) / 2 <= p) ++f;
        while (f * (f - 1) / 2 > p) --f;
        const int j = p - f * (f - 1) / 2;
        // Q layout [p][u2=xj][u1=xf][c], uint units (8 nibbles each)
        qoff[p] = ((p * NU + xs[j]) * NU + xs[f]) * 16;
        ws_[p]  = wbuf[(f - 1) * NF + j] * QSTEP;
    }
    __syncthreads();

    float acc[8] = {0.f, 0.f, 0.f, 0.f, 0.f, 0.f, 0.f, 0.f};
    float accS = 0.f;

    // pair terms: w*(q*QSTEP + QMIN) = ws*q - 7.5*ws
    for (int p = gg; p < NP; p += 8) {
        const unsigned int qv = Qu[qoff[p] + sub];
        const float w = ws_[p];
        accS += w;
        acc[0] += w * (float)(qv & 15u);
        acc[1] += w * (float)((qv >> 4) & 15u);
        acc[2] += w * (float)((qv >> 8) & 15u);
        acc[3] += w * (float)((qv >> 12) & 15u);
        acc[4] += w * (float)((qv >> 16) & 15u);
        acc[5] += w * (float)((qv >> 20) & 15u);
        acc[6] += w * (float)((qv >> 24) & 15u);
        acc[7] += w * (float)(qv >> 28);
    }
    accS *= -7.5f;
    #pragma unroll
    for (int k = 0; k < 8; ++k) acc[k] += accS;

    // folded feature/class/lse terms from G2 (768 KB, cache-resident)
    #pragma unroll
    for (int f = gg; f < NF; f += 8) {
        const float* gp = g2 + ((size_t)f * NU + xs[f]) * NC + c8;
        const float4 a = *(const float4*)(gp);
        const float4 bb = *(const float4*)(gp + 4);
        acc[0] += a.x; acc[1] += a.y; acc[2] += a.z; acc[3] += a.w;
        acc[4] += bb.x; acc[5] += bb.y; acc[6] += bb.z; acc[7] += bb.w;
    }

    *(float4*)(&sred[gg][c8])     = *(float4*)(&acc[0]);
    *(float4*)(&sred[gg][c8 + 4]) = *(float4*)(&acc[4]);
    __syncthreads();

    float v = 0.f;
    #pragma unroll
    for (int k = 0; k < 8; ++k) v += sred[k][t];
    out[(size_t)b * NC + t] = v;
}

extern "C" void kernel_launch(void* const* d_in, const int* in_sizes, int n_in,
                              void* d_out, int out_size, void* d_ws, size_t ws_size,
                              hipStream_t stream) {
    const int*   x                = (const int*)  d_in[0];
    const float* class_logits     = (const float*)d_in[1];
    const float* feature_logits   = (const float*)d_in[2];
    const float* aug_logits       = (const float*)d_in[3];
    const float* structure_logits = (const float*)d_in[4];
    const float* noise_uniform    = (const float*)d_in[5];
    float* out = (float*)d_out;

    unsigned short* Q4 = (unsigned short*)d_ws;               // 69 MB
    const size_t qushorts = (size_t)NP * NU * NU * NC / 4;
    float* lse_t = (float*)(Q4 + qushorts);                   // NP*NU*NC floats (9 MB)
    float* wbuf  = lse_t + (size_t)NP * NU * NC;              // (NF-1)*NF
    float* g2    = wbuf + (NF - 1) * NF;                      // NF*NU*NC (768 KB)

    kf_build<<<NF, NC, 0, stream>>>(feature_logits, class_logits,
                                    structure_logits, noise_uniform, g2, wbuf);
    k1_quant<<<NP * NU, 128, 0, stream>>>(aug_logits, Q4, lse_t);
    kg_fold<<<NF * NU, NC, 0, stream>>>(lse_t, wbuf, g2);
    k2_gather<<<NB, NC, 0, stream>>>(x, (const unsigned int*)Q4, g2, wbuf, out);
}

// Round 8
// 204.281 us; speedup vs baseline: 1.0474x; 1.0474x over previous
//
#include <hip/hip_runtime.h>
#include <math.h>

#define NF 24
#define NU 64
#define NC 128
#define NB 8192
#define NP 276          // NF*(NF-1)/2
#define EPSV 1e-6f
#define QMIN  (-0.1f)
#define QSTEP (0.2f / 15.f)
#define QINV  (15.f / 0.2f)

// ---------------- KF: fused feature-LSE + structure weights + G2 fold. 24 blocks x 128 thr -------
__global__ void __launch_bounds__(NC)
kf_build(const float* __restrict__ feat,
         const float* __restrict__ class_logits,
         const float* __restrict__ structure_logits,
         const float* __restrict__ noise_uniform,
         float* __restrict__ g2,
         float* __restrict__ wbuf) {
    const int f = blockIdx.x;            // [0, NF)
    const int t = threadIdx.x;           // 128
    const int l = t & 31, g = t >> 5, c4 = l * 4;

    __shared__ float slice[NU][NC];      // 32 KB
    __shared__ float lse_sh[NC];
    __shared__ float cls[NC];
    __shared__ float weff_sh;

    #pragma unroll
    for (int i = 0; i < 16; ++i) {
        const int u = g * 16 + i;
        *(float4*)(&slice[u][c4]) =
            *(const float4*)(feat + ((size_t)f * NU + u) * NC + c4);
    }
    if (f == 0) cls[t] = class_logits[t];
    __syncthreads();

    float s = 0.f;
    #pragma unroll 8
    for (int u = 0; u < NU; ++u) s += __expf(slice[u][t]);
    lse_sh[t] = logf(s);

    if (t == 0) {
        if (f == 0) { weff_sh = 1.f; }
        else {
            const int i = f - 1;
            float z[NF]; float m = -INFINITY;
            #pragma unroll
            for (int j = 0; j < NF; ++j) {
                const float uu = noise_uniform[i * NF + j];
                const float gg = -logf(-logf(uu + EPSV) + EPSV);
                float zz = structure_logits[i * NF + j] + gg;
                if (j > f) zz = -1e30f;
                z[j] = zz; m = fmaxf(m, zz);
            }
            float ss = 0.f;
            #pragma unroll
            for (int j = 0; j < NF; ++j) { z[j] = __expf(z[j] - m); ss += z[j]; }
            weff_sh = z[f] / ss;
        }
    }
    if (f == 0 && t < NF - 1) {
        const int i = t;
        float z[NF]; float m = -INFINITY;
        #pragma unroll
        for (int j = 0; j < NF; ++j) {
            const float uu = noise_uniform[i * NF + j];
            const float gg = -logf(-logf(uu + EPSV) + EPSV);
            float zz = structure_logits[i * NF + j] + gg;
            if (j > i + 1) zz = -1e30f;
            z[j] = zz; m = fmaxf(m, zz);
        }
        float ss = 0.f;
        #pragma unroll
        for (int j = 0; j < NF; ++j) { z[j] = __expf(z[j] - m); ss += z[j]; }
        const float inv = 1.f / ss;
        #pragma unroll
        for (int j = 0; j < NF; ++j) wbuf[i * NF + j] = z[j] * inv;
    }
    __syncthreads();

    const float weff = weff_sh;
    float lcls = 0.f;
    if (f == 0) {
        float sc = 0.f;
        #pragma unroll
        for (int i = 0; i < NC; ++i) sc += __expf(cls[i]);
        lcls = logf(sc);
    }

    const float4 L = *(const float4*)(&lse_sh[c4]);
    #pragma unroll
    for (int i = 0; i < 16; ++i) {
        const int u = g * 16 + i;
        const float4 v = *(const float4*)(&slice[u][c4]);
        float4 r;
        r.x = weff * (v.x - L.x); r.y = weff * (v.y - L.y);
        r.z = weff * (v.z - L.z); r.w = weff * (v.w - L.w);
        if (f == 0) {
            const float4 cv = *(const float4*)(&cls[c4]);
            r.x += cv.x - lcls; r.y += cv.y - lcls;
            r.z += cv.z - lcls; r.w += cv.w - lcls;
        }
        *(float4*)(g2 + ((size_t)f * NU + u) * NC + c4) = r;
    }
}

// ---------------- K1q: two-phase — read burst (exp-acc + quant to regs), then write burst ---------
// Block per (p,u2). Q layout [p][u2][u1][c] nibbles -> block writes contiguous 4 KB.
__global__ void __launch_bounds__(128)
k1_quant(const float* __restrict__ aug,
         unsigned short* __restrict__ Q4,
         float* __restrict__ lse_t) {
    const int pu2 = blockIdx.x;              // p*64 + u2
    const int p = pu2 >> 6, u2 = pu2 & 63;
    const int t = threadIdx.x;
    const int l = t & 31, g = t >> 5;        // group owns 16 u1's
    const int c4 = l * 4;

    __shared__ float sred[4][NC];

    const float* rb = aug + ((size_t)p * 4096 + u2) * NC + c4;   // [p][u1][u2][c4]

    float4 acc = {0.f, 0.f, 0.f, 0.f};
    unsigned short qreg[16];

    // Phase 1: pure read burst; quantize into registers
    #pragma unroll
    for (int i = 0; i < 16; ++i) {
        const int u1 = g * 16 + i;
        const float4 v = *(const float4*)(rb + (size_t)u1 * 8192);
        acc.x += __expf(v.x); acc.y += __expf(v.y);
        acc.z += __expf(v.z); acc.w += __expf(v.w);
        const unsigned int q0 = (unsigned int)fminf(fmaxf(rintf((v.x - QMIN) * QINV), 0.f), 15.f);
        const unsigned int q1 = (unsigned int)fminf(fmaxf(rintf((v.y - QMIN) * QINV), 0.f), 15.f);
        const unsigned int q2 = (unsigned int)fminf(fmaxf(rintf((v.z - QMIN) * QINV), 0.f), 15.f);
        const unsigned int q3 = (unsigned int)fminf(fmaxf(rintf((v.w - QMIN) * QINV), 0.f), 15.f);
        qreg[i] = (unsigned short)(q0 | (q1 << 4) | (q2 << 8) | (q3 << 12));
    }

    // Phase 2: pure write burst (coalesced 64 B per instruction, 4 KB per block)
    unsigned short* qb = Q4 + (size_t)pu2 * 2048 + l;
    #pragma unroll
    for (int i = 0; i < 16; ++i) {
        qb[(g * 16 + i) * 32] = qreg[i];
    }

    // lse reduce across groups
    *(float4*)(&sred[g][c4]) = acc;
    __syncthreads();
    if (g == 0) {
        const float4 r0 = *(const float4*)(&sred[0][c4]);
        const float4 r1 = *(const float4*)(&sred[1][c4]);
        const float4 r2 = *(const float4*)(&sred[2][c4]);
        const float4 r3 = *(const float4*)(&sred[3][c4]);
        float4 L;
        L.x = logf(r0.x + r1.x + r2.x + r3.x);
        L.y = logf(r0.y + r1.y + r2.y + r3.y);
        L.z = logf(r0.z + r1.z + r2.z + r3.z);
        L.w = logf(r0.w + r1.w + r2.w + r3.w);
        *(float4*)(lse_t + (size_t)pu2 * NC + c4) = L;
    }
}

// ---------------- KG: fold gathered-lse sums into G2 (in place) ----------------
__global__ void __launch_bounds__(NC)
kg_fold(const float* __restrict__ lse_t,
        const float* __restrict__ wbuf,
        float* __restrict__ g2) {
    const int blk = blockIdx.x;          // [0, NF*NU)
    const int f = blk >> 6, u = blk & 63;
    const int c = threadIdx.x;
    float acc = 0.f;
    for (int fp = f + 1; fp < NF; ++fp) {
        const int p = fp * (fp - 1) / 2 + f;
        acc -= wbuf[(fp - 1) * NF + f] * lse_t[((size_t)p * NU + u) * NC + c];
    }
    g2[((size_t)f * NU + u) * NC + c] += acc;
}

// ---------------- K2: per-batch gather from int4 table (R5 structure, no side table) -------------
__global__ void __launch_bounds__(NC)
k2_gather(const int* __restrict__ x,
          const unsigned short* __restrict__ Q4,
          const float* __restrict__ g2,
          const float* __restrict__ wbuf,
          float* __restrict__ out) {
    const int b = blockIdx.x;
    const int t = threadIdx.x;                 // 128
    const int g = t >> 5, l = t & 31, c4 = l * 4;

    __shared__ int   xs[NF];
    __shared__ int   qoff[NP];
    __shared__ float ws_[NP];
    __shared__ float sred[4][NC];

    if (t < NF) xs[t] = x[b * NF + t];
    __syncthreads();

    for (int p = t; p < NP; p += NC) {
        int f = (int)((sqrtf(8.0f * (float)p + 1.0f) - 1.0f) * 0.5f) + 1;
        while (f * (f + 1) / 2 <= p) ++f;
        while (f * (f - 1) / 2 > p) --f;
        const int j = p - f * (f - 1) / 2;
        // Q layout [p][u2=xj][u1=xf][c], ushort units
        qoff[p] = ((p * NU + xs[j]) * NU + xs[f]) * 32;
        ws_[p]  = wbuf[(f - 1) * NF + j] * QSTEP;
    }
    __syncthreads();

    float4 acc = {0.f, 0.f, 0.f, 0.f};
    float accS = 0.f;

    // folded feature/class/lse terms from G2 (768 KB, cache-resident)
    for (int f = g; f < NF; f += 4) {
        const float4 gv = *(const float4*)(g2 + ((size_t)f * NU + xs[f]) * NC + c4);
        acc.x += gv.x; acc.y += gv.y; acc.z += gv.z; acc.w += gv.w;
    }

    // pair terms: w*(q*QSTEP + QMIN) = ws*q - 7.5*ws
    #pragma unroll 4
    for (int p = g; p < NP; p += 4) {
        const unsigned int qv = Q4[qoff[p] + l];
        const float w = ws_[p];
        accS += w;
        acc.x += w * (float)(qv & 15u);
        acc.y += w * (float)((qv >> 4) & 15u);
        acc.z += w * (float)((qv >> 8) & 15u);
        acc.w += w * (float)(qv >> 12);
    }
    accS *= -7.5f;
    acc.x += accS; acc.y += accS; acc.z += accS; acc.w += accS;

    *(float4*)(&sred[g][c4]) = acc;
    __syncthreads();

    out[(size_t)b * NC + t] = sred[0][t] + sred[1][t] + sred[2][t] + sred[3][t];
}

extern "C" void kernel_launch(void* const* d_in, const int* in_sizes, int n_in,
                              void* d_out, int out_size, void* d_ws, size_t ws_size,
                              hipStream_t stream) {
    const int*   x                = (const int*)  d_in[0];
    const float* class_logits     = (const float*)d_in[1];
    const float* feature_logits   = (const float*)d_in[2];
    const float* aug_logits       = (const float*)d_in[3];
    const float* structure_logits = (const float*)d_in[4];
    const float* noise_uniform    = (const float*)d_in[5];
    float* out = (float*)d_out;

    unsigned short* Q4 = (unsigned short*)d_ws;               // 69 MB
    const size_t qushorts = (size_t)NP * NU * NU * NC / 4;
    float* lse_t = (float*)(Q4 + qushorts);                   // NP*NU*NC floats (9 MB)
    float* wbuf  = lse_t + (size_t)NP * NU * NC;              // (NF-1)*NF
    float* g2    = wbuf + (NF - 1) * NF;                      // NF*NU*NC (768 KB)

    kf_build<<<NF, NC, 0, stream>>>(feature_logits, class_logits,
                                    structure_logits, noise_uniform, g2, wbuf);
    k1_quant<<<NP * NU, 128, 0, stream>>>(aug_logits, Q4, lse_t);
    kg_fold<<<NF * NU, NC, 0, stream>>>(lse_t, wbuf, g2);
    k2_gather<<<NB, NC, 0, stream>>>(x, Q4, g2, wbuf, out);
}

// Round 9
// 192.065 us; speedup vs baseline: 1.1141x; 1.0636x over previous
//
#include <hip/hip_runtime.h>
#include <math.h>

#define NF 24
#define NU 64
#define NC 128
#define NB 8192
#define NP 276          // NF*(NF-1)/2
#define EPSV 1e-6f
#define QMIN  (-0.1f)
#define QSTEP (0.2f / 15.f)
#define QINV  (15.f / 0.2f)

// ---------------- KF: fused feature-LSE + structure weights + G2 fold. 24 blocks x 128 thr -------
__global__ void __launch_bounds__(NC)
kf_build(const float* __restrict__ feat,
         const float* __restrict__ class_logits,
         const float* __restrict__ structure_logits,
         const float* __restrict__ noise_uniform,
         float* __restrict__ g2,
         float* __restrict__ wbuf) {
    const int f = blockIdx.x;            // [0, NF)
    const int t = threadIdx.x;           // 128
    const int l = t & 31, g = t >> 5, c4 = l * 4;

    __shared__ float slice[NU][NC];      // 32 KB
    __shared__ float lse_sh[NC];
    __shared__ float cls[NC];
    __shared__ float weff_sh;

    #pragma unroll
    for (int i = 0; i < 16; ++i) {
        const int u = g * 16 + i;
        *(float4*)(&slice[u][c4]) =
            *(const float4*)(feat + ((size_t)f * NU + u) * NC + c4);
    }
    if (f == 0) cls[t] = class_logits[t];
    __syncthreads();

    float s = 0.f;
    #pragma unroll 8
    for (int u = 0; u < NU; ++u) s += __expf(slice[u][t]);
    lse_sh[t] = logf(s);

    if (t == 0) {
        if (f == 0) { weff_sh = 1.f; }
        else {
            const int i = f - 1;
            float z[NF]; float m = -INFINITY;
            #pragma unroll
            for (int j = 0; j < NF; ++j) {
                const float uu = noise_uniform[i * NF + j];
                const float gg = -logf(-logf(uu + EPSV) + EPSV);
                float zz = structure_logits[i * NF + j] + gg;
                if (j > f) zz = -1e30f;
                z[j] = zz; m = fmaxf(m, zz);
            }
            float ss = 0.f;
            #pragma unroll
            for (int j = 0; j < NF; ++j) { z[j] = __expf(z[j] - m); ss += z[j]; }
            weff_sh = z[f] / ss;
        }
    }
    if (f == 0 && t < NF - 1) {
        const int i = t;
        float z[NF]; float m = -INFINITY;
        #pragma unroll
        for (int j = 0; j < NF; ++j) {
            const float uu = noise_uniform[i * NF + j];
            const float gg = -logf(-logf(uu + EPSV) + EPSV);
            float zz = structure_logits[i * NF + j] + gg;
            if (j > i + 1) zz = -1e30f;
            z[j] = zz; m = fmaxf(m, zz);
        }
        float ss = 0.f;
        #pragma unroll
        for (int j = 0; j < NF; ++j) { z[j] = __expf(z[j] - m); ss += z[j]; }
        const float inv = 1.f / ss;
        #pragma unroll
        for (int j = 0; j < NF; ++j) wbuf[i * NF + j] = z[j] * inv;
    }
    __syncthreads();

    const float weff = weff_sh;
    float lcls = 0.f;
    if (f == 0) {
        float sc = 0.f;
        #pragma unroll
        for (int i = 0; i < NC; ++i) sc += __expf(cls[i]);
        lcls = logf(sc);
    }

    const float4 L = *(const float4*)(&lse_sh[c4]);
    #pragma unroll
    for (int i = 0; i < 16; ++i) {
        const int u = g * 16 + i;
        const float4 v = *(const float4*)(&slice[u][c4]);
        float4 r;
        r.x = weff * (v.x - L.x); r.y = weff * (v.y - L.y);
        r.z = weff * (v.z - L.z); r.w = weff * (v.w - L.w);
        if (f == 0) {
            const float4 cv = *(const float4*)(&cls[c4]);
            r.x += cv.x - lcls; r.y += cv.y - lcls;
            r.z += cv.z - lcls; r.w += cv.w - lcls;
        }
        *(float4*)(g2 + ((size_t)f * NU + u) * NC + c4) = r;
    }
}

// ---------------- K1q: R5 skeleton — LDS slice staging, barrier-separated read/write bursts ------
// One block per (p,u2). Phase 1: read burst into LDS + exp-acc. Phase 2: quant from LDS + store.
// Q layout [p][u2][u1][c] nibbles -> block writes contiguous 4 KB.
__global__ void __launch_bounds__(128)
k1_quant(const float* __restrict__ aug,
         unsigned short* __restrict__ Q4,
         float* __restrict__ lse_t) {
    const int pu2 = blockIdx.x;              // p*64 + u2
    const int p = pu2 >> 6, u2 = pu2 & 63;
    const int t = threadIdx.x;
    const int l = t & 31, g = t >> 5;        // group owns 16 u1's
    const int c4 = l * 4;

    __shared__ float slice[NU][NC];          // 32 KB  (also caps occupancy ~4 blocks/CU)
    __shared__ float sred[4][NC];            // 2 KB

    const float* rb = aug + ((size_t)p * 4096 + u2) * NC + c4;   // [p][u1][u2][c4]

    // Phase 1: pure read burst; stage to LDS; exp-accumulate
    float4 acc = {0.f, 0.f, 0.f, 0.f};
    #pragma unroll
    for (int i = 0; i < 16; ++i) {
        const int u1 = g * 16 + i;
        const float4 v = *(const float4*)(rb + (size_t)u1 * 8192);
        *(float4*)(&slice[u1][c4]) = v;
        acc.x += __expf(v.x); acc.y += __expf(v.y);
        acc.z += __expf(v.z); acc.w += __expf(v.w);
    }
    *(float4*)(&sred[g][c4]) = acc;
    __syncthreads();

    if (g == 0) {
        const float4 r0 = *(const float4*)(&sred[0][c4]);
        const float4 r1 = *(const float4*)(&sred[1][c4]);
        const float4 r2 = *(const float4*)(&sred[2][c4]);
        const float4 r3 = *(const float4*)(&sred[3][c4]);
        float4 L;
        L.x = logf(r0.x + r1.x + r2.x + r3.x);
        L.y = logf(r0.y + r1.y + r2.y + r3.y);
        L.z = logf(r0.z + r1.z + r2.z + r3.z);
        L.w = logf(r0.w + r1.w + r2.w + r3.w);
        *(float4*)(lse_t + (size_t)pu2 * NC + c4) = L;
    }

    // Phase 2: quant from LDS + coalesced store burst
    unsigned short* qb = Q4 + (size_t)pu2 * 2048 + l;
    #pragma unroll
    for (int i = 0; i < 16; ++i) {
        const int u1 = g * 16 + i;
        const float4 v = *(const float4*)(&slice[u1][c4]);
        const unsigned int q0 = (unsigned int)fminf(fmaxf(rintf((v.x - QMIN) * QINV), 0.f), 15.f);
        const unsigned int q1 = (unsigned int)fminf(fmaxf(rintf((v.y - QMIN) * QINV), 0.f), 15.f);
        const unsigned int q2 = (unsigned int)fminf(fmaxf(rintf((v.z - QMIN) * QINV), 0.f), 15.f);
        const unsigned int q3 = (unsigned int)fminf(fmaxf(rintf((v.w - QMIN) * QINV), 0.f), 15.f);
        qb[u1 * 32] = (unsigned short)(q0 | (q1 << 4) | (q2 << 8) | (q3 << 12));
    }
}

// ---------------- KG: fold gathered-lse sums into G2 (in place) ----------------
__global__ void __launch_bounds__(NC)
kg_fold(const float* __restrict__ lse_t,
        const float* __restrict__ wbuf,
        float* __restrict__ g2) {
    const int blk = blockIdx.x;          // [0, NF*NU)
    const int f = blk >> 6, u = blk & 63;
    const int c = threadIdx.x;
    float acc = 0.f;
    for (int fp = f + 1; fp < NF; ++fp) {
        const int p = fp * (fp - 1) / 2 + f;
        acc -= wbuf[(fp - 1) * NF + f] * lse_t[((size_t)p * NU + u) * NC + c];
    }
    g2[((size_t)f * NU + u) * NC + c] += acc;
}

// ---------------- K2: per-batch gather from int4 table (R5 structure, no side table) -------------
__global__ void __launch_bounds__(NC)
k2_gather(const int* __restrict__ x,
          const unsigned short* __restrict__ Q4,
          const float* __restrict__ g2,
          const float* __restrict__ wbuf,
          float* __restrict__ out) {
    const int b = blockIdx.x;
    const int t = threadIdx.x;                 // 128
    const int g = t >> 5, l = t & 31, c4 = l * 4;

    __shared__ int   xs[NF];
    __shared__ int   qoff[NP];
    __shared__ float ws_[NP];
    __shared__ float sred[4][NC];

    if (t < NF) xs[t] = x[b * NF + t];
    __syncthreads();

    for (int p = t; p < NP; p += NC) {
        int f = (int)((sqrtf(8.0f * (float)p + 1.0f) - 1.0f) * 0.5f) + 1;
        while (f * (f + 1) / 2 <= p) ++f;
        while (f * (f - 1) / 2 > p) --f;
        const int j = p - f * (f - 1) / 2;
        // Q layout [p][u2=xj][u1=xf][c], ushort units
        qoff[p] = ((p * NU + xs[j]) * NU + xs[f]) * 32;
        ws_[p]  = wbuf[(f - 1) * NF + j] * QSTEP;
    }
    __syncthreads();

    float4 acc = {0.f, 0.f, 0.f, 0.f};
    float accS = 0.f;

    // folded feature/class/lse terms from G2 (768 KB, cache-resident)
    for (int f = g; f < NF; f += 4) {
        const float4 gv = *(const float4*)(g2 + ((size_t)f * NU + xs[f]) * NC + c4);
        acc.x += gv.x; acc.y += gv.y; acc.z += gv.z; acc.w += gv.w;
    }

    // pair terms: w*(q*QSTEP + QMIN) = ws*q - 7.5*ws
    #pragma unroll 4
    for (int p = g; p < NP; p += 4) {
        const unsigned int qv = Q4[qoff[p] + l];
        const float w = ws_[p];
        accS += w;
        acc.x += w * (float)(qv & 15u);
        acc.y += w * (float)((qv >> 4) & 15u);
        acc.z += w * (float)((qv >> 8) & 15u);
        acc.w += w * (float)(qv >> 12);
    }
    accS *= -7.5f;
    acc.x += accS; acc.y += accS; acc.z += accS; acc.w += accS;

    *(float4*)(&sred[g][c4]) = acc;
    __syncthreads();

    out[(size_t)b * NC + t] = sred[0][t] + sred[1][t] + sred[2][t] + sred[3][t];
}

extern "C" void kernel_launch(void* const* d_in, const int* in_sizes, int n_in,
                              void* d_out, int out_size, void* d_ws, size_t ws_size,
                              hipStream_t stream) {
    const int*   x                = (const int*)  d_in[0];
    const float* class_logits     = (const float*)d_in[1];
    const float* feature_logits   = (const float*)d_in[2];
    const float* aug_logits       = (const float*)d_in[3];
    const float* structure_logits = (const float*)d_in[4];
    const float* noise_uniform    = (const float*)d_in[5];
    float* out = (float*)d_out;

    unsigned short* Q4 = (unsigned short*)d_ws;               // 69 MB
    const size_t qushorts = (size_t)NP * NU * NU * NC / 4;
    float* lse_t = (float*)(Q4 + qushorts);                   // NP*NU*NC floats (9 MB)
    float* wbuf  = lse_t + (size_t)NP * NU * NC;              // (NF-1)*NF
    float* g2    = wbuf + (NF - 1) * NF;                      // NF*NU*NC (768 KB)

    kf_build<<<NF, NC, 0, stream>>>(feature_logits, class_logits,
                                    structure_logits, noise_uniform, g2, wbuf);
    k1_quant<<<NP * NU, 128, 0, stream>>>(aug_logits, Q4, lse_t);
    kg_fold<<<NF * NU, NC, 0, stream>>>(lse_t, wbuf, g2);
    k2_gather<<<NB, NC, 0, stream>>>(x, Q4, g2, wbuf, out);
}